// Round 1
// 109.272 us; speedup vs baseline: 1.0110x; 1.0110x over previous
//
#include <hip/hip_runtime.h>
#include <math.h>

// Problem constants (B=1)
#define S 2048
#define DM 512
#define WIN 64
#define ATTN_SCALE 0.17677669529663687f   // 1/sqrt(32)

typedef __attribute__((ext_vector_type(8))) short short8;   // 8 x bf16 (4 VGPR)
typedef __attribute__((ext_vector_type(4))) float floatx4;  // MFMA acc

__device__ __forceinline__ unsigned short f2bf(float f) {
  unsigned int u = __float_as_uint(f);
  unsigned int r = (u + 0x7FFFu + ((u >> 16) & 1u)) >> 16;   // RNE
  return (unsigned short)r;
}

// ---------------------------------------------------------------------------
// Convert x (S*DM floats) and Wq|Wk|Wv|Wo (4 * DM*DM) to bf16.
// ---------------------------------------------------------------------------
__global__ __launch_bounds__(256) void convert_bf16(
    const float* __restrict__ x, const float* __restrict__ Wq,
    const float* __restrict__ Wk, const float* __restrict__ Wv,
    const float* __restrict__ Wo,
    unsigned short* __restrict__ xbf, unsigned short* __restrict__ wbf) {
  size_t i4 = ((size_t)blockIdx.x * 256 + threadIdx.x) * 4;
  const float* src; unsigned short* dst; size_t off;
  const size_t NX = (size_t)S * DM;           // 1,048,576
  if (i4 < NX) {
    src = x; dst = xbf; off = i4;
  } else {
    size_t r = i4 - NX;
    int wsel = (int)(r >> 18);                // / (512*512)
    src = wsel == 0 ? Wq : wsel == 1 ? Wk : wsel == 2 ? Wv : Wo;
    dst = wbf + ((size_t)wsel << 18);
    off = r & 262143;
  }
  float4 f = *(const float4*)(src + off);
  ushort4 o;
  o.x = f2bf(f.x); o.y = f2bf(f.y); o.z = f2bf(f.z); o.w = f2bf(f.w);
  *(ushort4*)(dst + off) = o;
}

// ---------------------------------------------------------------------------
// bf16 MFMA GEMM: C[M,N] = A[M,K] * B[N,K]^T  (fp32 accumulate/output).
// 64x64 block tile, BK=64, 256 threads = 4 waves in 2x2, each wave 32x32
// via 2x2 of mfma_f32_16x16x32_bf16. blockIdx.z selects B/C plane (QKV).
// LDS granule XOR-swizzle: row r, 16B-granule g stored at g ^ (r & 7).
// ---------------------------------------------------------------------------
__global__ __launch_bounds__(256) void gemm_bf16(
    const unsigned short* __restrict__ Abf,
    const unsigned short* __restrict__ Bbase, int bstride,
    float* __restrict__ Cbase, int cstride,
    int M, int N, int K) {
  __shared__ unsigned short As[64 * 64];
  __shared__ unsigned short Bs[64 * 64];

  const unsigned short* B = Bbase + (size_t)blockIdx.z * bstride;
  float* C = Cbase + (size_t)blockIdx.z * cstride;

  const int row0 = blockIdx.y * 64;
  const int col0 = blockIdx.x * 64;
  const int tid  = threadIdx.x;
  const int lane = tid & 63;
  const int w    = tid >> 6;       // wave id 0..3
  const int wr   = w >> 1;         // wave row 0..1
  const int wc   = w & 1;          // wave col 0..1
  const int quad = lane >> 4;      // 0..3
  const int lc   = lane & 15;

  // staging map: thread -> (row srow, 16B granule tid&7), covers 32 rows/pass
  const int srow = tid >> 3;
  const int sg   = tid & 7;                    // granule within row
  const int scol = sg * 8;                     // element col in global tile
  const int sw0  = (sg ^ (srow & 7)) * 8;      // swizzled LDS elem col

  floatx4 acc[2][2] = {};

  for (int k0 = 0; k0 < K; k0 += 64) {
    short8 a0 = *(const short8*)&Abf[(size_t)(row0 + srow) * K + k0 + scol];
    short8 a1 = *(const short8*)&Abf[(size_t)(row0 + srow + 32) * K + k0 + scol];
    short8 b0 = *(const short8*)&B[(size_t)(col0 + srow) * K + k0 + scol];
    short8 b1 = *(const short8*)&B[(size_t)(col0 + srow + 32) * K + k0 + scol];
    __syncthreads();   // previous iteration's LDS reads complete
    *(short8*)&As[srow * 64 + sw0] = a0;
    *(short8*)&As[(srow + 32) * 64 + sw0] = a1;   // (srow+32)&7 == srow&7
    *(short8*)&Bs[srow * 64 + sw0] = b0;
    *(short8*)&Bs[(srow + 32) * 64 + sw0] = b1;
    __syncthreads();

#pragma unroll
    for (int s = 0; s < 2; ++s) {
      const int gk = s * 4 + quad;            // k-granule 0..7
      short8 aF[2], bF[2];
#pragma unroll
      for (int i = 0; i < 2; ++i) {
        int m = wr * 32 + i * 16 + lc;
        aF[i] = *(const short8*)&As[m * 64 + (gk ^ (m & 7)) * 8];
      }
#pragma unroll
      for (int j = 0; j < 2; ++j) {
        int n = wc * 32 + j * 16 + lc;
        bF[j] = *(const short8*)&Bs[n * 64 + (gk ^ (n & 7)) * 8];
      }
#pragma unroll
      for (int i = 0; i < 2; ++i)
#pragma unroll
        for (int j = 0; j < 2; ++j)
          acc[i][j] = __builtin_amdgcn_mfma_f32_16x16x32_bf16(
              aF[i], bF[j], acc[i][j], 0, 0, 0);
    }
  }

  // C/D layout: col = lane&15, row = quad*4 + reg  [verified m89/m91]
#pragma unroll
  for (int i = 0; i < 2; ++i)
#pragma unroll
    for (int j = 0; j < 2; ++j) {
      int col = col0 + wc * 32 + j * 16 + lc;
#pragma unroll
      for (int r = 0; r < 4; ++r) {
        int row = row0 + wr * 32 + i * 16 + quad * 4 + r;
        C[(size_t)row * N + col] = acc[i][j][r];
      }
    }
}

// ---------------------------------------------------------------------------
// Sliding-window per-channel softmax, LDS-tiled.
// Block = 64 query rows x 32 channels. Stages the k/v panel
// rows [i0-63, i0+63] x 32 ch (127 x 32 fp32, 2 x 16.25 KB LDS) once;
// fetch multiplicity drops 64x -> ~2x. LDS reads are conflict-free
// (bank = c & 31, 2 lanes/bank). Only the i0==0 block pays the validity
// mask (uniform branch). Shift-invariant softmax (no max subtraction,
// |s| <= ~6 so fp32 exp is safe). Writes bf16 for the out-proj GEMM.
// ---------------------------------------------------------------------------
#define SWIN_ITEM(EDGE)                                                       \
  {                                                                           \
    float l0 = 0.f, l1 = 0.f, l2 = 0.f, l3 = 0.f;                             \
    float a0 = 0.f, a1 = 0.f, a2 = 0.f, a3 = 0.f;                             \
    _Pragma("unroll 4")                                                       \
    for (int jj = 0; jj < WIN; jj += 4) {                                     \
      _Pragma("unroll")                                                       \
      for (int u = 0; u < 4; ++u) {                                           \
        const float kv = ks[base + (jj + u) * 32];                            \
        const float vv = vs[base + (jj + u) * 32];                            \
        float p = __expf(qv * kv);                                            \
        if (EDGE) p = (jj + u >= th) ? p : 0.f;                               \
        const float pv = p * vv;                                              \
        if (u == 0)      { l0 += p; a0 += pv; }                               \
        else if (u == 1) { l1 += p; a1 += pv; }                               \
        else if (u == 2) { l2 += p; a2 += pv; }                               \
        else             { l3 += p; a3 += pv; }                               \
      }                                                                       \
    }                                                                         \
    const float r = (a0 + a1 + a2 + a3) / (l0 + l1 + l2 + l3);                \
    o[(size_t)(i0 + ii) * DM + c] = f2bf(r);                                  \
  }

__global__ __launch_bounds__(256) void swin_attn_tiled(
    const float* __restrict__ q, const float* __restrict__ k,
    const float* __restrict__ v, unsigned short* __restrict__ o) {
  __shared__ float ks[127 * 32];
  __shared__ float vs[127 * 32];

  const int i0 = blockIdx.y * 64;      // query-row tile
  const int c0 = blockIdx.x * 32;      // channel tile
  const int t  = threadIdx.x;

  // Stage k,v rows [i0-63, i0+63] x cols [c0, c0+32).  127 rows x 8 float4
  // per array = 2032 float4 loads across 256 threads (~8 each), coalesced
  // in 128 B row segments.
  for (int vi = t; vi < 2 * 127 * 8; vi += 256) {
    const int a = vi >= 1016;                    // 0: k, 1: v
    const int r = (vi - (a ? 1016 : 0)) >> 3;    // panel row 0..126
    const int g = vi & 7;                        // float4 within row
    int gr = i0 - 63 + r;
    gr = gr < 0 ? 0 : gr;                        // clamp (masked in compute)
    const float4 f =
        *(const float4*)((a ? v : k) + (size_t)gr * DM + c0 + g * 4);
    *(float4*)((a ? vs : ks) + (r << 5) + g * 4) = f;
  }
  __syncthreads();

  const int cl = t & 31;
  const int c  = c0 + cl;

  if (blockIdx.y == 0) {
#pragma unroll
    for (int item = 0; item < 8; ++item) {
      const int ii = (t >> 5) + item * 8;                 // 0..63
      const float qv = q[(size_t)(i0 + ii) * DM + c] * ATTN_SCALE;
      const int base = ii * 32 + cl;                      // LDS row ii..ii+63
      const int th = 63 - ii;                             // jj >= th is valid
      SWIN_ITEM(true)
    }
  } else {
#pragma unroll
    for (int item = 0; item < 8; ++item) {
      const int ii = (t >> 5) + item * 8;
      const float qv = q[(size_t)(i0 + ii) * DM + c] * ATTN_SCALE;
      const int base = ii * 32 + cl;
      const int th = 0;                                   // unused
      SWIN_ITEM(false)
    }
  }
}

// ---------------------------------------------------------------------------
// Launch
// ---------------------------------------------------------------------------
extern "C" void kernel_launch(void* const* d_in, const int* in_sizes, int n_in,
                              void* d_out, int out_size, void* d_ws, size_t ws_size,
                              hipStream_t stream) {
  const float* x  = (const float*)d_in[0];
  const float* Wq = (const float*)d_in[1];
  const float* Wk = (const float*)d_in[2];
  const float* Wv = (const float*)d_in[3];
  const float* Wo = (const float*)d_in[4];
  float* out = (float*)d_out;

  // ws layout (16 MB total):
  //   q, k, v : 3 x 1M fp32 (12 MB)
  //   xbf     : 1M bf16 (2 MB)  -- reused as attn_bf16 after qkv GEMM
  //   wbf     : 4 x 256K bf16 (2 MB)
  float* q = (float*)d_ws;
  float* kk = q + (size_t)S * DM;
  float* vv = kk + (size_t)S * DM;
  unsigned short* xbf = (unsigned short*)(vv + (size_t)S * DM);
  unsigned short* wbf = xbf + (size_t)S * DM;
  unsigned short* attnbf = xbf;   // reuse after x is consumed

  // 1) fp32 -> bf16 conversions (2M elements, 4/thread)
  convert_bf16<<<dim3(2048), dim3(256), 0, stream>>>(x, Wq, Wk, Wv, Wo, xbf, wbf);

  // 2) fused QKV: C_z = x * W_z^T, z = 0,1,2
  gemm_bf16<<<dim3(DM / 64, S / 64, 3), dim3(256), 0, stream>>>(
      xbf, wbf, DM * DM, q, S * DM, S, DM, DM);

  // 3) sliding-window per-channel softmax (LDS-tiled) -> bf16
  swin_attn_tiled<<<dim3(DM / 32, S / 64), dim3(256), 0, stream>>>(
      q, kk, vv, attnbf);

  // 4) output projection: out = attn * Wo^T
  gemm_bf16<<<dim3(DM / 64, S / 64, 1), dim3(256), 0, stream>>>(
      attnbf, wbf + 3 * (size_t)DM * DM, 0, out, 0, S, DM, DM);
}